// Round 2
// baseline (1740.782 us; speedup 1.0000x reference)
//
#include <hip/hip_runtime.h>

// ScaledDotProductAttention: B=4,H=16,S=2048,D=64, fp32 in/out.
// v3: (1) mask packed to bits (512KB, L2-resident) by a prepass kernel into
// d_ws; (2) zero main-loop LDS: swapped QK^T D-layout [k=q4*4+r][q=c15] IS the
// A-fragment of mfma_f32_16x16x16f16, so PV runs per-wave over its own k-slice
// straight from registers; V B-frags read direct from global (L2-warm).
// Both phases barrier-free; one ds_add_f32 O-reduction at kernel end.

namespace {
constexpr int Bn = 4, Hn = 16, Sn = 2048, Dn = 64;
constexpr int QB = 64;           // q-rows per workgroup
constexpr int KT = 64;           // k-rows per iteration (16 per wave)
constexpr int NIT = Sn / KT;     // 32
constexpr int NWG = (Sn / QB) * Hn * Bn;  // 2048
constexpr int MW  = Sn / 64;     // 32 mask words per row
}

using half8   = __attribute__((ext_vector_type(8))) _Float16;
using half4   = __attribute__((ext_vector_type(4))) _Float16;
using float4v = __attribute__((ext_vector_type(4))) float;
typedef unsigned long long u64;

__device__ __forceinline__ half8 cvt_half8(float4v a, float4v b) {
    half8 f;
    f[0] = (_Float16)a[0]; f[1] = (_Float16)a[1];
    f[2] = (_Float16)a[2]; f[3] = (_Float16)a[3];
    f[4] = (_Float16)b[0]; f[5] = (_Float16)b[1];
    f[6] = (_Float16)b[2]; f[7] = (_Float16)b[3];
    return f;
}

// ---- prepass: int32 mask [S][S] -> bitmask u64 [S][MW] (bit=1 -> masked) ----
__global__ __launch_bounds__(256) void mask_pack(const int* __restrict__ Mg,
                                                 u64* __restrict__ Wb)
{
    const int gw   = (blockIdx.x * 256 + threadIdx.x) >> 6;  // word id
    const int lane = threadIdx.x & 63;
    const int row  = gw >> 5, wi = gw & 31;
    const u64 bal  = __ballot(Mg[(size_t)row * Sn + wi * 64 + lane] != 0);
    if (lane == 0) Wb[(size_t)row * MW + wi] = bal;
}

__global__ __launch_bounds__(256, 3) void attn_fused(
    const float* __restrict__ Qg, const float* __restrict__ Kg,
    const float* __restrict__ Vg, const u64* __restrict__ Wb,
    float* __restrict__ Og, float* __restrict__ Pg)
{
    __shared__ float lrow[QB];
    __shared__ float Olds[QB][68];   // pad 68: 2-way ds_add pattern (free)

    const int tid  = threadIdx.x;
    const int w    = tid >> 6;    // wave 0..3 -> k-slice w*16..w*16+15
    const int lane = tid & 63;
    const int c15  = lane & 15;
    const int q4   = lane >> 4;
    const int sh   = w * 16 + q4 * 4;   // this lane's k-offset within a KT tile

    // XCD-chunked remap: each XCD gets contiguous wids -> ~3 heads concurrent
    // per XCD (K+V 3MB + mask bits 0.5MB ~ one 4MB L2).
    const int L    = blockIdx.x + (int)gridDim.x * (blockIdx.y + (int)gridDim.y * blockIdx.z);
    const int wid  = (L & 7) * (NWG / 8) + (L >> 3);
    const int qblk = wid & (Sn / QB - 1);
    const int h    = (wid / (Sn / QB)) & (Hn - 1);
    const int b    = wid / ((Sn / QB) * Hn);
    const int qbase = qblk * QB;

    const size_t headoff = ((size_t)(b * Hn + h)) * Sn * Dn;
    const float* Qh = Qg + headoff + (size_t)qbase * Dn;
    const float* Kh = Kg + headoff;
    const float* Vh = Vg + headoff;
    float*       Oh = Og + headoff + (size_t)qbase * Dn;
    const u64*   Mb = Wb + (size_t)(qbase + c15) * MW;
    float*       Pb = Pg + ((size_t)(b * Hn + h)) * Sn * Sn
                    + (size_t)(qbase + c15) * Sn + sh;

    if (tid < QB) lrow[tid] = 0.f;

    // ---- Q fragments direct from global ----
    half8 qfr[8];
    #pragma unroll
    for (int m = 0; m < 4; ++m) {
        #pragma unroll
        for (int ks = 0; ks < 2; ++ks) {
            const float* p = Qh + (size_t)(m * 16 + c15) * Dn + ks * 32 + q4 * 8;
            qfr[m * 2 + ks] = cvt_half8(*(const float4v*)p, *(const float4v*)(p + 4));
        }
    }
    __syncthreads();   // lrow init visible before phase-A atomics

    // ================= phase A: row denominators (barrier-free) ================
    const float* Kp = Kh + (size_t)(w * 16 + c15) * Dn + q4 * 8;
    float4v k0 = *(const float4v*)(Kp);
    float4v k1 = *(const float4v*)(Kp + 4);
    float4v k2 = *(const float4v*)(Kp + 32);
    float4v k3 = *(const float4v*)(Kp + 36);
    float lsum[4] = {0.f, 0.f, 0.f, 0.f};

    for (int t = 0; t < NIT; ++t) {
        const half8 a0 = cvt_half8(k0, k1);
        const half8 a1 = cvt_half8(k2, k3);
        if (t != NIT - 1) {
            Kp += KT * Dn;
            k0 = *(const float4v*)(Kp);
            k1 = *(const float4v*)(Kp + 4);
            k2 = *(const float4v*)(Kp + 32);
            k3 = *(const float4v*)(Kp + 36);
        }
        #pragma unroll
        for (int mb = 0; mb < 4; ++mb) {
            const u64 ms = Mb[(size_t)(mb * 16) * MW + t] >> sh;
            float4v D = {0.f, 0.f, 0.f, 0.f};
            D = __builtin_amdgcn_mfma_f32_16x16x32_f16(a0, qfr[2 * mb + 0], D, 0, 0, 0);
            D = __builtin_amdgcn_mfma_f32_16x16x32_f16(a1, qfr[2 * mb + 1], D, 0, 0, 0);
            lsum[mb] += ((ms      & 1) ? 0.f : __expf(D[0] * 0.125f))
                      + ((ms >> 1 & 1) ? 0.f : __expf(D[1] * 0.125f))
                      + ((ms >> 2 & 1) ? 0.f : __expf(D[2] * 0.125f))
                      + ((ms >> 3 & 1) ? 0.f : __expf(D[3] * 0.125f));
        }
    }
    #pragma unroll
    for (int mb = 0; mb < 4; ++mb) {
        lsum[mb] += __shfl_xor(lsum[mb], 16);
        lsum[mb] += __shfl_xor(lsum[mb], 32);
    }
    if (lane < 16) {
        #pragma unroll
        for (int mb = 0; mb < 4; ++mb) atomicAdd(&lrow[mb * 16 + lane], lsum[mb]);
    }
    __syncthreads();
    if (tid < QB) lrow[tid] = 1.f / lrow[tid];
    __syncthreads();
    float linv[4];
    #pragma unroll
    for (int mb = 0; mb < 4; ++mb) linv[mb] = lrow[mb * 16 + c15];

    // ================= phase B: P export + per-wave k-slice PV (barrier-free) ==
    float4v Of[16];   // Of[mb*4+db] -> O[mb*16 + q4*4+r][db*16 + c15] partial
    #pragma unroll
    for (int i = 0; i < 16; ++i) Of[i] = {0.f, 0.f, 0.f, 0.f};

    const float* Vb0 = Vh + (size_t)(w * 16 + q4 * 4) * Dn + c15;

    #pragma unroll 1
    for (int t = 0; t < NIT; ++t) {
        const float* Kt = Kh + (size_t)(t * KT + w * 16 + c15) * Dn + q4 * 8;
        const float4v kk0 = *(const float4v*)(Kt);
        const float4v kk1 = *(const float4v*)(Kt + 4);
        const float4v kk2 = *(const float4v*)(Kt + 32);
        const float4v kk3 = *(const float4v*)(Kt + 36);
        // V B-frag elements: V[t*64 + w*16 + q4*4 + j][db*16 + c15]
        const float* Vt = Vb0 + (size_t)t * KT * Dn;
        float v[16];
        #pragma unroll
        for (int j = 0; j < 4; ++j)
            #pragma unroll
            for (int db = 0; db < 4; ++db)
                v[j * 4 + db] = Vt[j * Dn + db * 16];
        u64 ms[4];
        #pragma unroll
        for (int mb = 0; mb < 4; ++mb) ms[mb] = Mb[(size_t)(mb * 16) * MW + t] >> sh;

        const half8 a0 = cvt_half8(kk0, kk1);
        const half8 a1 = cvt_half8(kk2, kk3);
        half4 ph0, ph1, ph2, ph3;
        #pragma unroll
        for (int mb = 0; mb < 4; ++mb) {
            float4v D = {0.f, 0.f, 0.f, 0.f};
            D = __builtin_amdgcn_mfma_f32_16x16x32_f16(a0, qfr[2 * mb + 0], D, 0, 0, 0);
            D = __builtin_amdgcn_mfma_f32_16x16x32_f16(a1, qfr[2 * mb + 1], D, 0, 0, 0);
            float4v pw;
            pw[0] = (ms[mb]      & 1) ? 0.f : __expf(D[0] * 0.125f) * linv[mb];
            pw[1] = (ms[mb] >> 1 & 1) ? 0.f : __expf(D[1] * 0.125f) * linv[mb];
            pw[2] = (ms[mb] >> 2 & 1) ? 0.f : __expf(D[2] * 0.125f) * linv[mb];
            pw[3] = (ms[mb] >> 3 & 1) ? 0.f : __expf(D[3] * 0.125f) * linv[mb];
            __builtin_nontemporal_store(pw,
                (float4v*)(Pb + (size_t)(mb * 16) * Sn + t * KT));
            half4 hp;
            hp[0] = (_Float16)pw[0]; hp[1] = (_Float16)pw[1];
            hp[2] = (_Float16)pw[2]; hp[3] = (_Float16)pw[3];
            if (mb == 0) ph0 = hp; else if (mb == 1) ph1 = hp;
            else if (mb == 2) ph2 = hp; else ph3 = hp;
        }
        #pragma unroll
        for (int db = 0; db < 4; ++db) {
            half4 bf;
            bf[0] = (_Float16)v[ 0 + db];
            bf[1] = (_Float16)v[ 4 + db];
            bf[2] = (_Float16)v[ 8 + db];
            bf[3] = (_Float16)v[12 + db];
            Of[0 * 4 + db] = __builtin_amdgcn_mfma_f32_16x16x16f16(ph0, bf, Of[0 * 4 + db], 0, 0, 0);
            Of[1 * 4 + db] = __builtin_amdgcn_mfma_f32_16x16x16f16(ph1, bf, Of[1 * 4 + db], 0, 0, 0);
            Of[2 * 4 + db] = __builtin_amdgcn_mfma_f32_16x16x16f16(ph2, bf, Of[2 * 4 + db], 0, 0, 0);
            Of[3 * 4 + db] = __builtin_amdgcn_mfma_f32_16x16x16f16(ph3, bf, Of[3 * 4 + db], 0, 0, 0);
        }
    }

    // ---- cross-wave O reduction in LDS, then coalesced write ----
    __syncthreads();
    for (int i = tid; i < QB * 68; i += 256) ((float*)Olds)[i] = 0.f;
    __syncthreads();
    #pragma unroll
    for (int mb = 0; mb < 4; ++mb)
        #pragma unroll
        for (int db = 0; db < 4; ++db)
            #pragma unroll
            for (int r = 0; r < 4; ++r)
                atomicAdd(&Olds[mb * 16 + q4 * 4 + r][db * 16 + c15],
                          Of[mb * 4 + db][r]);
    __syncthreads();
    const int orow = tid >> 2, ocol = (tid & 3) << 4;
    #pragma unroll
    for (int cc = 0; cc < 16; cc += 4) {
        *(float4v*)(Oh + (size_t)orow * Dn + ocol + cc) =
            *(const float4v*)&Olds[orow][ocol + cc];
    }
}

extern "C" void kernel_launch(void* const* d_in, const int* in_sizes, int n_in,
                              void* d_out, int out_size, void* d_ws, size_t ws_size,
                              hipStream_t stream) {
    (void)in_sizes; (void)n_in; (void)ws_size; (void)out_size;
    // setup_inputs order: key, query, value, mask
    const float* Kg = (const float*)d_in[0];
    const float* Qg = (const float*)d_in[1];
    const float* Vg = (const float*)d_in[2];
    const int*   Mg = (const int*)d_in[3];
    float* Og = (float*)d_out;                              // output  [B,H,S,D]
    float* Pg = Og + (size_t)Bn * Hn * Sn * Dn;             // attention [B,H,S,S]
    u64*   Wb = (u64*)d_ws;                                 // 512KB bitmask

    // prepass: S*MW = 65536 words, one wave each -> 16384 blocks of 256
    mask_pack<<<dim3(Sn * MW / 4), dim3(256), 0, stream>>>(Mg, Wb);

    dim3 grid(Sn / QB, Hn, Bn), block(256);
    attn_fused<<<grid, block, 0, stream>>>(Qg, Kg, Vg, Wb, Og, Pg);
}